// Round 6
// baseline (1208.215 us; speedup 1.0000x reference)
//
#include <hip/hip_runtime.h>
#include <math.h>

typedef _Float16 f16;
typedef _Float16 f16x4 __attribute__((ext_vector_type(4)));
typedef _Float16 f16x8 __attribute__((ext_vector_type(8)));
typedef float f32x16 __attribute__((ext_vector_type(16)));

// ---------------------------------------------------------------------------
// Repack weights (96, V, K) fp32 -> wpack[t][ch][VP] f16, zero-padded v >= V.
// ---------------------------------------------------------------------------
template<int V, int K, int VP>
__global__ void repack_kernel(const float* __restrict__ w, f16* __restrict__ wp) {
    int i = blockIdx.x * 256 + threadIdx.x;
    if (i >= K * 96 * VP) return;
    int v = i % VP, ch = (i / VP) % 96, t = i / (VP * 96);
    float val = (v < V) ? w[(ch * V + v) * K + t] : 0.f;
    wp[i] = (f16)val;
}

// ---------------------------------------------------------------------------
// PROTEIN. Round-2 register structure (wave owns ONE 32-ch col-tile, bf=64
// VGPR -- the only profile that never spilled) + chunked double-buffered
// register-staged pipeline (T14) to overlap staging with MFMA.
// 6 waves: colw = wave%3, roww = wave/3 (4 row-tiles each per chunk).
// Chunk = 256 output rows; buffer 264 rows x 80 B; 2 buffers = 42.2 KB
// -> 2 blocks/CU, 12 waves/CU. launch_bounds(384,3) caps regs at 170.
// Per-tile acc split into 2 chains (ks=0/1 partial sums) to halve MFMA
// dependency latency; summed before the masked max.
// ---------------------------------------------------------------------------
__global__ __launch_bounds__(384, 3) void conv_pro_kernel(
    const float* __restrict__ in,    // (B, 25, 1000) f32
    const f16*   __restrict__ wp,    // (8, 96, 32) f16
    const float* __restrict__ bias,  // (96)
    float* __restrict__ feat,        // (B, 192)
    int feat_off)
{
    constexpr int V = 25, L = 1000, KT = 8, VP = 32, LOUT = 993;
    constexpr int C    = 256;          // output rows per chunk
    constexpr int NC   = 4;            // chunks (4*256 = 1024 >= 993+7)
    constexpr int BR   = 264;          // buffer rows (C + taps, rounded)
    constexpr int RSB  = 80;           // row stride bytes (64 B payload + pad)
    constexpr int BUFB = BR * RSB;     // 21120 B
    constexpr int NIT  = 7 * BR;       // staging units (7 vocab-quads)
    constexpr int MAXU = (NIT + 383) / 384;   // 5

    __shared__ __align__(16) char s_raw[2 * BUFB];   // 42.2 KB
    __shared__ float s_red[2 * 96];

    const int tid  = threadIdx.x;
    const int wave = tid >> 6;
    const int lane = tid & 63;
    const int colw = wave % 3;
    const int roww = wave / 3;
    const int q    = lane >> 5;        // k-half
    const int r    = lane & 31;        // row/col in 32-tile
    const size_t b = blockIdx.x;

    // ---- weights: my col-tile only, 8 taps x 2 ksteps (64 VGPR) ----
    f16x8 bf[KT][2];
    #pragma unroll
    for (int t = 0; t < KT; ++t)
        #pragma unroll
        for (int ks = 0; ks < 2; ++ks)
            bf[t][ks] = *(const f16x8*)(wp + (t * 96 + colw * 32 + r) * VP + ks * 16 + q * 8);

    // ---- register staging (20 VGPR) ----
    const float* gs = in + b * (size_t)(V * L);
    float rs[MAXU][4];
    auto do_loads = [&](int c) {
        const int g0 = c * C;
        #pragma unroll
        for (int u = 0; u < MAXU; ++u) {
            int uu = u * 384 + tid;
            int q4 = uu / BR, p = uu - q4 * BR;
            int gp = g0 + p;
            bool ok = (uu < NIT) && (gp < L);
            #pragma unroll
            for (int j = 0; j < 4; ++j) {
                int v = q4 * 4 + j;
                rs[u][j] = (ok && v < V) ? gs[(size_t)v * L + gp] : 0.f;
            }
        }
    };
    auto do_write = [&](int bsel) {
        char* sb = s_raw + bsel * BUFB;
        #pragma unroll
        for (int u = 0; u < MAXU; ++u) {
            int uu = u * 384 + tid;
            if (uu < NIT) {
                int q4 = uu / BR, p = uu - q4 * BR;
                int swz = ((p >> 3) & 3) << 4;
                char* dst = sb + p * RSB;
                if (q4 < 6) {
                    f16x4 hv = { (f16)rs[u][0], (f16)rs[u][1], (f16)rs[u][2], (f16)rs[u][3] };
                    *(f16x4*)(dst + ((8 * q4) ^ swz)) = hv;
                } else {               // tail: v=24 + zero pad v25..31
                    f16x8 hv = {};
                    hv[0] = (f16)rs[u][0];
                    *(f16x8*)(dst + (48 ^ swz)) = hv;
                }
            }
        }
    };

    // ---- pipeline prologue ----
    do_loads(0);
    do_write(0);
    do_loads(1);
    __syncthreads();

    float runmax = -3.0e38f;

    for (int c = 0; c < NC; ++c) {
        const char* sb = s_raw + (c & 1) * BUFB;
        #pragma unroll
        for (int tt = 0; tt < 4; ++tt) {
            const int tile = roww * 4 + tt;
            f32x16 acc0 = {}, acc1 = {};           // 2 chains (ks split)
            #pragma unroll
            for (int t = 0; t < KT; ++t) {
                const int row = tile * 32 + r + t;   // <= 262 < BR
                const int swz = ((row >> 3) & 3) << 4;
                const char* ap = sb + row * RSB;
                f16x8 af0 = *(const f16x8*)(ap + ((q * 16) ^ swz));
                f16x8 af1 = *(const f16x8*)(ap + ((32 + q * 16) ^ swz));
                acc0 = __builtin_amdgcn_mfma_f32_32x32x16_f16(af0, bf[t][0], acc0, 0, 0, 0);
                acc1 = __builtin_amdgcn_mfma_f32_32x32x16_f16(af1, bf[t][1], acc1, 0, 0, 0);
            }
            const int p0g = c * C + tile * 32;
            if (p0g + 32 <= LOUT) {
                #pragma unroll
                for (int i = 0; i < 16; ++i)
                    runmax = fmaxf(runmax, acc0[i] + acc1[i]);
            } else {
                #pragma unroll
                for (int i = 0; i < 16; ++i) {
                    const int rr = (i & 3) + 8 * (i >> 2) + 4 * q;  // C/D row
                    if (p0g + rr < LOUT) runmax = fmaxf(runmax, acc0[i] + acc1[i]);
                }
            }
        }
        if (c + 1 < NC) {
            __syncthreads();                  // all waves done reading
            do_write((c + 1) & 1);
            if (c + 2 < NC) do_loads(c + 2);
            __syncthreads();                  // staging visible
        }
    }

    // ---- reduce: lanes r / r+32 hold col colw*32+r for row-groups ----
    runmax = fmaxf(runmax, __shfl_xor(runmax, 32, 64));
    if (lane < 32) s_red[roww * 96 + colw * 32 + r] = runmax;
    __syncthreads();
    if (tid < 96) {
        float m = fmaxf(s_red[tid], s_red[96 + tid]);
        feat[b * 192 + feat_off + tid] = fmaxf(m + bias[tid], 0.f);
    }
}

// ---------------------------------------------------------------------------
// LIGAND branch: round-2 kernel (proven; ~30 us).
// ---------------------------------------------------------------------------
__global__ __launch_bounds__(384) void conv_lig_kernel(
    const float* __restrict__ in,    // (B, 64, 100) f32
    const f16*   __restrict__ wp,    // (4, 96, 64) f16
    const float* __restrict__ bias,  // (96)
    float* __restrict__ feat,        // (B, 192)
    int feat_off)
{
    constexpr int V = 64, L = 100, KT = 4, VP = 64, KSTEPS = 4;
    constexpr int LP = 132, RS = 72, NTILES = 4, LOUT = 97;
    constexpr int RSB = RS * 2, NQ = V / 4;
    __shared__ __align__(16) char s_raw[LP * RSB];

    const int tid  = threadIdx.x;
    const int b    = blockIdx.x;
    const int wave = tid >> 6;
    const int lane = tid & 63;
    const int colw = wave % 3;
    const int roww = wave / 3;
    const int q    = lane >> 5;
    const int r    = lane & 31;

    {   // zero LDS (covers row pad)
        float4 z = {0.f, 0.f, 0.f, 0.f};
        float4* sz = (float4*)s_raw;
        for (int i = tid; i < LP * RSB / 16; i += 384) sz[i] = z;
    }
    __syncthreads();

    const float* gin = in + (size_t)b * (V * L);
    for (int i = tid; i < NQ * L; i += 384) {
        int q4 = i / L, p = i - q4 * L;
        const float* gp = gin + q4 * 4 * L + p;
        f16x4 hv = { (f16)gp[0], (f16)gp[L], (f16)gp[2 * L], (f16)gp[3 * L] };
        int off = (8 * q4) ^ (((p >> 3) & 3) << 4);
        *(f16x4*)(s_raw + p * RSB + off) = hv;
    }

    f16x8 bfr[KT][KSTEPS];
    #pragma unroll
    for (int t = 0; t < KT; ++t)
        #pragma unroll
        for (int ks = 0; ks < KSTEPS; ++ks)
            bfr[t][ks] = *(const f16x8*)(wp + (t * 96 + colw * 32 + r) * VP + ks * 16 + q * 8);

    __syncthreads();

    float runmax = -3.0e38f;
    for (int it = 0; it < NTILES / 2; ++it) {
        const int p0 = (roww * (NTILES / 2) + it) * 32;
        f32x16 acc = {};
        #pragma unroll
        for (int t = 0; t < KT; ++t) {
            int row = p0 + r + t;
            if (row > LP - 1) row = LP - 1;          // clamped row is zero
            const char* ap = s_raw + row * RSB;
            const int swz = ((row >> 3) & 3) << 4;
            #pragma unroll
            for (int ks = 0; ks < KSTEPS; ++ks) {
                f16x8 af = *(const f16x8*)(ap + ((ks * 32 + q * 16) ^ swz));
                acc = __builtin_amdgcn_mfma_f32_32x32x16_f16(af, bfr[t][ks], acc, 0, 0, 0);
            }
        }
        #pragma unroll
        for (int i = 0; i < 16; ++i) {
            int rr = (i & 3) + 8 * (i >> 2) + 4 * q;
            if (p0 + rr < LOUT) runmax = fmaxf(runmax, acc[i]);
        }
    }
    runmax = fmaxf(runmax, __shfl_xor(runmax, 32, 64));

    __syncthreads();
    float* s_red = (float*)s_raw;     // [2][96]
    if (lane < 32) s_red[roww * 96 + colw * 32 + r] = runmax;
    __syncthreads();
    if (tid < 96) {
        float m = fmaxf(s_red[tid], s_red[96 + tid]);
        feat[(size_t)b * 192 + feat_off + tid] = fmaxf(m + bias[tid], 0.f);
    }
}

// ---------------------------------------------------------------------------
// Gram + L2 normalize + readout (4 samples/block, one wave each).
// ---------------------------------------------------------------------------
__global__ __launch_bounds__(256) void gram_affinity_kernel(
    const float* __restrict__ feat, const float* __restrict__ w_aff,
    const float* __restrict__ b_aff, float* __restrict__ out, int B)
{
    const int lane = threadIdx.x & 63;
    const int wid  = threadIdx.x >> 6;
    const int b    = blockIdx.x * 4 + wid;

    __shared__ float s_x[4][192];

    if (b < B) {
        const float* fp = feat + (size_t)b * 192;
        for (int i = lane; i < 192; i += 64) s_x[wid][i] = fp[i];
    }
    __syncthreads();

    if (b < B) {
        float ssum = 0.f, sdot = 0.f;
        #pragma unroll
        for (int t = 0; t < 16; ++t) {
            const int jk = t * 64 + lane;
            const int j = jk >> 5, k = jk & 31;
            float gg = 0.f;
            #pragma unroll
            for (int i = 0; i < 6; ++i)
                gg = fmaf(s_x[wid][i * 32 + j], s_x[wid][i * 32 + k], gg);
            ssum = fmaf(gg, gg, ssum);
            sdot = fmaf(gg, w_aff[jk], sdot);
        }
        #pragma unroll
        for (int off = 32; off >= 1; off >>= 1) {
            ssum += __shfl_xor(ssum, off, 64);
            sdot += __shfl_xor(sdot, off, 64);
        }
        if (lane == 0) out[b] = sdot / (sqrtf(ssum) + 1e-12f) + b_aff[0];
    }
}

extern "C" void kernel_launch(void* const* d_in, const int* in_sizes, int n_in,
                              void* d_out, int out_size, void* d_ws, size_t ws_size,
                              hipStream_t stream)
{
    const float* protein = (const float*)d_in[0];  // (B, 25, 1000)
    const float* ligand  = (const float*)d_in[1];  // (B, 64, 100)
    const float* w_pro   = (const float*)d_in[2];  // (96, 25, 8)
    const float* b_pro   = (const float*)d_in[3];  // (96,)
    const float* w_lig   = (const float*)d_in[4];  // (96, 64, 4)
    const float* b_lig   = (const float*)d_in[5];  // (96,)
    const float* w_aff   = (const float*)d_in[6];  // (1024,)
    const float* b_aff   = (const float*)d_in[7];  // (1,)
    float* out = (float*)d_out;
    const int B = out_size;                        // 4096

    float* feat   = (float*)d_ws;                              // (B,192) f32
    f16*   wpackP = (f16*)((char*)d_ws + (size_t)B * 192 * 4); // 8*96*32 f16
    f16*   wpackL = wpackP + 8 * 96 * 32;                      // 4*96*64 f16

    repack_kernel<25, 8, 32><<<96, 256, 0, stream>>>(w_pro, wpackP);
    repack_kernel<64, 4, 64><<<96, 256, 0, stream>>>(w_lig, wpackL);

    // ligand branch -> feat[:, 0:96]
    conv_lig_kernel<<<B, 384, 0, stream>>>(ligand, wpackL, b_lig, feat, 0);
    // protein branch -> feat[:, 96:192]
    conv_pro_kernel<<<B, 384, 0, stream>>>(protein, wpackP, b_pro, feat, 96);

    gram_affinity_kernel<<<(B + 3) / 4, 256, 0, stream>>>(feat, w_aff, b_aff, out, B);
}

// Round 7
// 704.138 us; speedup vs baseline: 1.7159x; 1.7159x over previous
//
#include <hip/hip_runtime.h>
#include <math.h>

typedef _Float16 f16;
typedef _Float16 f16x4 __attribute__((ext_vector_type(4)));
typedef _Float16 f16x8 __attribute__((ext_vector_type(8)));
typedef float f32x16 __attribute__((ext_vector_type(16)));

// ---------------------------------------------------------------------------
// Repack weights (96, V, K) fp32 -> wpack[t][ch][VP] f16, zero-padded v >= V.
// ---------------------------------------------------------------------------
template<int V, int K, int VP>
__global__ void repack_kernel(const float* __restrict__ w, f16* __restrict__ wp) {
    int i = blockIdx.x * 256 + threadIdx.x;
    if (i >= K * 96 * VP) return;
    int v = i % VP, ch = (i / VP) % 96, t = i / (VP * 96);
    float val = (v < V) ? w[(ch * V + v) * K + t] : 0.f;
    wp[i] = (f16)val;
}

// ---------------------------------------------------------------------------
// PROTEIN. Round-2 register discipline (bf=64 VGPR; staging via TRANSIENT
// regs only -- nothing lives across a barrier => nothing to spill), chunked
// into 4 x 256 output rows with a SINGLE 264-row buffer (21.1 KB LDS).
// Overlap comes from cross-block concurrency (~5 blocks/CU): while one
// block stages from HBM, co-resident blocks run MFMA.
// 192 threads = 3 waves; wave = col-tile (32 ch); each wave does all 8
// row-tiles per chunk. acc split in 2 ks-chains for MFMA dep-latency.
// ---------------------------------------------------------------------------
__global__ __launch_bounds__(192, 4) void conv_pro_kernel(
    const float* __restrict__ in,    // (B, 25, 1000) f32
    const f16*   __restrict__ wp,    // (8, 96, 32) f16
    const float* __restrict__ bias,  // (96)
    float* __restrict__ feat,        // (B, 192)
    int feat_off)
{
    constexpr int V = 25, L = 1000, KT = 8, VP = 32, LOUT = 993;
    constexpr int CH  = 256;           // output rows per chunk
    constexpr int NC  = 4;             // chunks
    constexpr int BR  = 264;           // buffer rows (256 outputs + 7 halo)
    constexpr int RSB = 80;            // row stride bytes (64 B payload + pad)
    constexpr int NIT = 7 * BR;        // staging units (6 quads + 1 tail-oct)

    __shared__ __align__(16) char s_raw[BR * RSB];   // 21.1 KB
    __shared__ float s_red[96];

    const int tid  = threadIdx.x;
    const int wave = tid >> 6;         // = col-tile (0..2)
    const int lane = tid & 63;
    const int q    = lane >> 5;        // k-half
    const int r    = lane & 31;        // row/col in 32-tile
    const size_t b = blockIdx.x;

    // ---- weights: my col-tile, 8 taps x 2 ksteps (64 VGPR) ----
    f16x8 bf[KT][2];
    #pragma unroll
    for (int t = 0; t < KT; ++t)
        #pragma unroll
        for (int ks = 0; ks < 2; ++ks)
            bf[t][ks] = *(const f16x8*)(wp + (t * 96 + wave * 32 + r) * VP + ks * 16 + q * 8);

    const float* gs = in + b * (size_t)(V * L);
    float runmax = -3.0e38f;

    for (int c = 0; c < NC; ++c) {
        __syncthreads();               // previous chunk's compute done
        // ---- stage chunk c: global -> cvt -> LDS, transient regs only ----
        for (int i = tid; i < NIT; i += 192) {
            const int q4 = i / BR, p = i - q4 * BR;
            const int gp = c * CH + p;
            const int swz = ((p >> 3) & 3) << 4;
            char* dst = s_raw + p * RSB;
            if (q4 < 6) {              // full quads v = 4q4..4q4+3
                f16x4 hv = {};
                if (gp < L) {
                    const float* g0 = gs + q4 * 4 * L + gp;
                    hv[0] = (f16)g0[0];     hv[1] = (f16)g0[L];
                    hv[2] = (f16)g0[2 * L]; hv[3] = (f16)g0[3 * L];
                }
                *(f16x4*)(dst + ((8 * q4) ^ swz)) = hv;
            } else {                   // tail oct: v=24 + zero pad v25..31
                f16x8 hv = {};
                if (gp < L) hv[0] = (f16)gs[24 * L + gp];
                *(f16x8*)(dst + (48 ^ swz)) = hv;
            }
        }
        __syncthreads();               // staging visible
        // ---- compute: 8 row-tiles, all by every wave (own col-tile) ----
        for (int tt = 0; tt < 8; ++tt) {
            f32x16 acc0 = {}, acc1 = {};
            #pragma unroll
            for (int t = 0; t < KT; ++t) {
                const int row = tt * 32 + r + t;        // <= 262 < BR
                const int swz = ((row >> 3) & 3) << 4;
                const char* ap = s_raw + row * RSB;
                f16x8 af0 = *(const f16x8*)(ap + ((q * 16) ^ swz));
                f16x8 af1 = *(const f16x8*)(ap + ((32 + q * 16) ^ swz));
                acc0 = __builtin_amdgcn_mfma_f32_32x32x16_f16(af0, bf[t][0], acc0, 0, 0, 0);
                acc1 = __builtin_amdgcn_mfma_f32_32x32x16_f16(af1, bf[t][1], acc1, 0, 0, 0);
            }
            const int p0g = c * CH + tt * 32;
            if (p0g + 32 <= LOUT) {
                #pragma unroll
                for (int i = 0; i < 16; ++i)
                    runmax = fmaxf(runmax, acc0[i] + acc1[i]);
            } else {
                #pragma unroll
                for (int i = 0; i < 16; ++i) {
                    const int rr = (i & 3) + 8 * (i >> 2) + 4 * q;  // C/D row
                    if (p0g + rr < LOUT) runmax = fmaxf(runmax, acc0[i] + acc1[i]);
                }
            }
        }
    }

    // ---- reduce: col = wave*32+r held by lanes r and r+32 ----
    runmax = fmaxf(runmax, __shfl_xor(runmax, 32, 64));
    if (lane < 32) s_red[wave * 32 + r] = runmax;
    __syncthreads();
    if (tid < 96)
        feat[b * 192 + feat_off + tid] = fmaxf(s_red[tid] + bias[tid], 0.f);
}

// ---------------------------------------------------------------------------
// LIGAND branch: round-2 kernel (proven; ~25 us).
// ---------------------------------------------------------------------------
__global__ __launch_bounds__(384) void conv_lig_kernel(
    const float* __restrict__ in,    // (B, 64, 100) f32
    const f16*   __restrict__ wp,    // (4, 96, 64) f16
    const float* __restrict__ bias,  // (96)
    float* __restrict__ feat,        // (B, 192)
    int feat_off)
{
    constexpr int V = 64, L = 100, KT = 4, VP = 64, KSTEPS = 4;
    constexpr int LP = 132, RS = 72, NTILES = 4, LOUT = 97;
    constexpr int RSB = RS * 2, NQ = V / 4;
    __shared__ __align__(16) char s_raw[LP * RSB];

    const int tid  = threadIdx.x;
    const int b    = blockIdx.x;
    const int wave = tid >> 6;
    const int lane = tid & 63;
    const int colw = wave % 3;
    const int roww = wave / 3;
    const int q    = lane >> 5;
    const int r    = lane & 31;

    {   // zero LDS (covers row pad)
        float4 z = {0.f, 0.f, 0.f, 0.f};
        float4* sz = (float4*)s_raw;
        for (int i = tid; i < LP * RSB / 16; i += 384) sz[i] = z;
    }
    __syncthreads();

    const float* gin = in + (size_t)b * (V * L);
    for (int i = tid; i < NQ * L; i += 384) {
        int q4 = i / L, p = i - q4 * L;
        const float* gp = gin + q4 * 4 * L + p;
        f16x4 hv = { (f16)gp[0], (f16)gp[L], (f16)gp[2 * L], (f16)gp[3 * L] };
        int off = (8 * q4) ^ (((p >> 3) & 3) << 4);
        *(f16x4*)(s_raw + p * RSB + off) = hv;
    }

    f16x8 bfr[KT][KSTEPS];
    #pragma unroll
    for (int t = 0; t < KT; ++t)
        #pragma unroll
        for (int ks = 0; ks < KSTEPS; ++ks)
            bfr[t][ks] = *(const f16x8*)(wp + (t * 96 + colw * 32 + r) * VP + ks * 16 + q * 8);

    __syncthreads();

    float runmax = -3.0e38f;
    for (int it = 0; it < NTILES / 2; ++it) {
        const int p0 = (roww * (NTILES / 2) + it) * 32;
        f32x16 acc = {};
        #pragma unroll
        for (int t = 0; t < KT; ++t) {
            int row = p0 + r + t;
            if (row > LP - 1) row = LP - 1;          // clamped row is zero
            const char* ap = s_raw + row * RSB;
            const int swz = ((row >> 3) & 3) << 4;
            #pragma unroll
            for (int ks = 0; ks < KSTEPS; ++ks) {
                f16x8 af = *(const f16x8*)(ap + ((ks * 32 + q * 16) ^ swz));
                acc = __builtin_amdgcn_mfma_f32_32x32x16_f16(af, bfr[t][ks], acc, 0, 0, 0);
            }
        }
        #pragma unroll
        for (int i = 0; i < 16; ++i) {
            int rr = (i & 3) + 8 * (i >> 2) + 4 * q;
            if (p0 + rr < LOUT) runmax = fmaxf(runmax, acc[i]);
        }
    }
    runmax = fmaxf(runmax, __shfl_xor(runmax, 32, 64));

    __syncthreads();
    float* s_red = (float*)s_raw;     // [2][96]
    if (lane < 32) s_red[roww * 96 + colw * 32 + r] = runmax;
    __syncthreads();
    if (tid < 96) {
        float m = fmaxf(s_red[tid], s_red[96 + tid]);
        feat[(size_t)b * 192 + feat_off + tid] = fmaxf(m + bias[tid], 0.f);
    }
}

// ---------------------------------------------------------------------------
// Gram + L2 normalize + readout (4 samples/block, one wave each).
// ---------------------------------------------------------------------------
__global__ __launch_bounds__(256) void gram_affinity_kernel(
    const float* __restrict__ feat, const float* __restrict__ w_aff,
    const float* __restrict__ b_aff, float* __restrict__ out, int B)
{
    const int lane = threadIdx.x & 63;
    const int wid  = threadIdx.x >> 6;
    const int b    = blockIdx.x * 4 + wid;

    __shared__ float s_x[4][192];

    if (b < B) {
        const float* fp = feat + (size_t)b * 192;
        for (int i = lane; i < 192; i += 64) s_x[wid][i] = fp[i];
    }
    __syncthreads();

    if (b < B) {
        float ssum = 0.f, sdot = 0.f;
        #pragma unroll
        for (int t = 0; t < 16; ++t) {
            const int jk = t * 64 + lane;
            const int j = jk >> 5, k = jk & 31;
            float gg = 0.f;
            #pragma unroll
            for (int i = 0; i < 6; ++i)
                gg = fmaf(s_x[wid][i * 32 + j], s_x[wid][i * 32 + k], gg);
            ssum = fmaf(gg, gg, ssum);
            sdot = fmaf(gg, w_aff[jk], sdot);
        }
        #pragma unroll
        for (int off = 32; off >= 1; off >>= 1) {
            ssum += __shfl_xor(ssum, off, 64);
            sdot += __shfl_xor(sdot, off, 64);
        }
        if (lane == 0) out[b] = sdot / (sqrtf(ssum) + 1e-12f) + b_aff[0];
    }
}

extern "C" void kernel_launch(void* const* d_in, const int* in_sizes, int n_in,
                              void* d_out, int out_size, void* d_ws, size_t ws_size,
                              hipStream_t stream)
{
    const float* protein = (const float*)d_in[0];  // (B, 25, 1000)
    const float* ligand  = (const float*)d_in[1];  // (B, 64, 100)
    const float* w_pro   = (const float*)d_in[2];  // (96, 25, 8)
    const float* b_pro   = (const float*)d_in[3];  // (96,)
    const float* w_lig   = (const float*)d_in[4];  // (96, 64, 4)
    const float* b_lig   = (const float*)d_in[5];  // (96,)
    const float* w_aff   = (const float*)d_in[6];  // (1024,)
    const float* b_aff   = (const float*)d_in[7];  // (1,)
    float* out = (float*)d_out;
    const int B = out_size;                        // 4096

    float* feat   = (float*)d_ws;                              // (B,192) f32
    f16*   wpackP = (f16*)((char*)d_ws + (size_t)B * 192 * 4); // 8*96*32 f16
    f16*   wpackL = wpackP + 8 * 96 * 32;                      // 4*96*64 f16

    repack_kernel<25, 8, 32><<<96, 256, 0, stream>>>(w_pro, wpackP);
    repack_kernel<64, 4, 64><<<96, 256, 0, stream>>>(w_lig, wpackL);

    // ligand branch -> feat[:, 0:96]
    conv_lig_kernel<<<B, 384, 0, stream>>>(ligand, wpackL, b_lig, feat, 0);
    // protein branch -> feat[:, 96:192]
    conv_pro_kernel<<<B, 192, 0, stream>>>(protein, wpackP, b_pro, feat, 96);

    gram_affinity_kernel<<<(B + 3) / 4, 256, 0, stream>>>(feat, w_aff, b_aff, out, B);
}

// Round 8
// 452.338 us; speedup vs baseline: 2.6710x; 1.5567x over previous
//
#include <hip/hip_runtime.h>
#include <math.h>

typedef _Float16 f16;
typedef _Float16 f16x4 __attribute__((ext_vector_type(4)));
typedef _Float16 f16x8 __attribute__((ext_vector_type(8)));
typedef float f32x4 __attribute__((ext_vector_type(4)));
typedef float f32x16 __attribute__((ext_vector_type(16)));

// ---------------------------------------------------------------------------
// Repack weights (96, V, K) fp32 -> wpack[t][ch][VP] f16, zero-padded v >= V.
// ---------------------------------------------------------------------------
template<int V, int K, int VP>
__global__ void repack_kernel(const float* __restrict__ w, f16* __restrict__ wp) {
    int i = blockIdx.x * 256 + threadIdx.x;
    if (i >= K * 96 * VP) return;
    int v = i % VP, ch = (i / VP) % 96, t = i / (VP * 96);
    float val = (v < V) ? w[(ch * V + v) * K + t] : 0.f;
    wp[i] = (f16)val;
}

// ---------------------------------------------------------------------------
// PROTEIN. 16x16x32 f16 MFMA: one A-fragment (b128, K=32=whole padded vocab)
// feeds 6 MFMAs (all 96 channels) -> MFMA-bound (LDS A-path has 2.4x
// headroom), no cross-wave A duplication.
// Tap loop OUTERMOST: only current tap's 6 B-frags live (24 VGPR). acc
// (4 row-tiles x 6 cols x f32x4 = 96 regs) lives only between barriers --
// nothing fat crosses a barrier => nothing to spill (r3-r6 lesson).
// Staging: 7 float4 loads/thread/chunk (wide, independent) + 4 b16
// transposed LDS writes each. Chunk = 256 rows, single 264-row buffer,
// 22.7 KB LDS; overlap via ~4-6 co-resident blocks/CU.
// ---------------------------------------------------------------------------
__global__ __launch_bounds__(256, 2) void conv_pro_kernel(
    const float* __restrict__ in,    // (B, 25, 1000) f32
    const f16*   __restrict__ wp,    // (8, 96, 32) f16
    const float* __restrict__ bias,  // (96)
    float* __restrict__ feat,        // (B, 192)
    int feat_off)
{
    constexpr int V = 25, L = 1000, KT = 8, LOUT = 993;
    constexpr int CH  = 256;          // output rows per chunk
    constexpr int NC  = 4;            // chunks
    constexpr int BR  = 264;          // buffer rows (256 + 7 halo, pad 264)
    constexpr int RSB = 80;           // row stride bytes (64 payload + 16 pad)
    constexpr int P4  = BR / 4;       // 66 p-quads per buffer
    constexpr int NU  = V * P4;       // 1650 staging units

    __shared__ __align__(16) char s_raw[BR * RSB];   // 21.1 KB
    __shared__ float s_red[4 * 96];

    const int tid  = threadIdx.x;
    const int wave = tid >> 6;
    const int lane = tid & 63;
    const int g    = lane >> 4;       // k-oct (0..3): k = g*8..g*8+7
    const int r16  = lane & 15;       // A-row / B-col within 16-tile
    const size_t b = blockIdx.x;
    const float* gs = in + b * (size_t)(V * L);

    // one-time: zero the v-pad slot (payload bytes 48..63, v=24..31) of every
    // row; staging rewrites v=24 (bytes 48-49) each chunk, v>=25 stays zero.
    for (int row = tid; row < BR; row += 256) {
        const int swz = ((row >> 3) & 3) << 4;
        *(f16x8*)(s_raw + row * RSB + (48 ^ swz)) = (f16x8){};
    }
    __syncthreads();    // pad zeros visible before chunk-0 staging writes v=24

    float runmax[6];
    #pragma unroll
    for (int c6 = 0; c6 < 6; ++c6) runmax[c6] = -3.0e38f;

    for (int c = 0; c < NC; ++c) {
        if (c) __syncthreads();       // previous chunk's compute done
        // ---- stage chunk c: unit = (vrow, p-quad), float4 along p ----
        #pragma unroll
        for (int u = 0; u < 7; ++u) {
            const int i = u * 256 + tid;
            if (i < NU) {
                const int vr = i / P4, p4 = i - vr * P4;
                const int p  = 4 * p4;
                const int gp = c * CH + p;
                float4 xv = {0.f, 0.f, 0.f, 0.f};
                if (gp < L) xv = *(const float4*)(gs + (size_t)vr * L + gp);
                const int pb   = 2 * vr;             // payload byte of column
                const int slot = pb & 48, sub = pb & 15;
                #pragma unroll
                for (int j = 0; j < 4; ++j) {
                    const int row = p + j;
                    const int swz = ((row >> 3) & 3) << 4;
                    float xj = (j == 0) ? xv.x : (j == 1) ? xv.y : (j == 2) ? xv.z : xv.w;
                    *(f16*)(s_raw + row * RSB + (slot ^ swz) + sub) = (f16)xj;
                }
            }
        }
        __syncthreads();              // staging visible
        // ---- compute: wave owns rows [wave*64, wave*64+63] (4 row-tiles) ----
        f32x4 acc[4][6] = {};
        #pragma unroll 1
        for (int t = 0; t < KT; ++t) {
            f16x8 bf[6];
            #pragma unroll
            for (int c6 = 0; c6 < 6; ++c6)
                bf[c6] = *(const f16x8*)(wp + (t * 96 + c6 * 16 + r16) * 32 + g * 8);
            #pragma unroll
            for (int rt = 0; rt < 4; ++rt) {
                const int row = wave * 64 + rt * 16 + r16 + t;   // <= 262 < BR
                const int swz = ((row >> 3) & 3) << 4;
                f16x8 a = *(const f16x8*)(s_raw + row * RSB + ((g * 16) ^ swz));
                #pragma unroll
                for (int c6 = 0; c6 < 6; ++c6)
                    acc[rt][c6] = __builtin_amdgcn_mfma_f32_16x16x32_f16(a, bf[c6], acc[rt][c6], 0, 0, 0);
            }
        }
        // ---- fold acc into runmax; C/D: col=lane&15, row=g*4+i ----
        #pragma unroll
        for (int rt = 0; rt < 4; ++rt) {
            const int p0g = c * CH + wave * 64 + rt * 16 + g * 4;
            #pragma unroll
            for (int c6 = 0; c6 < 6; ++c6)
                #pragma unroll
                for (int i = 0; i < 4; ++i)
                    if (p0g + i < LOUT) runmax[c6] = fmaxf(runmax[c6], acc[rt][c6][i]);
        }
    }

    // ---- reduce: channel c6*16+r16 held by g-groups {r16, +16, +32, +48} ----
    #pragma unroll
    for (int c6 = 0; c6 < 6; ++c6) {
        runmax[c6] = fmaxf(runmax[c6], __shfl_xor(runmax[c6], 16, 64));
        runmax[c6] = fmaxf(runmax[c6], __shfl_xor(runmax[c6], 32, 64));
    }
    if (lane < 16) {
        #pragma unroll
        for (int c6 = 0; c6 < 6; ++c6)
            s_red[wave * 96 + c6 * 16 + lane] = runmax[c6];
    }
    __syncthreads();
    if (tid < 96) {
        float m = fmaxf(fmaxf(s_red[tid], s_red[96 + tid]),
                        fmaxf(s_red[192 + tid], s_red[288 + tid]));
        feat[b * 192 + feat_off + tid] = fmaxf(m + bias[tid], 0.f);
    }
}

// ---------------------------------------------------------------------------
// LIGAND branch: round-2 kernel (proven; ~25 us).
// ---------------------------------------------------------------------------
__global__ __launch_bounds__(384) void conv_lig_kernel(
    const float* __restrict__ in,    // (B, 64, 100) f32
    const f16*   __restrict__ wp,    // (4, 96, 64) f16
    const float* __restrict__ bias,  // (96)
    float* __restrict__ feat,        // (B, 192)
    int feat_off)
{
    constexpr int V = 64, L = 100, KT = 4, VP = 64, KSTEPS = 4;
    constexpr int LP = 132, RS = 72, NTILES = 4, LOUT = 97;
    constexpr int RSB = RS * 2, NQ = V / 4;
    __shared__ __align__(16) char s_raw[LP * RSB];

    const int tid  = threadIdx.x;
    const int b    = blockIdx.x;
    const int wave = tid >> 6;
    const int lane = tid & 63;
    const int colw = wave % 3;
    const int roww = wave / 3;
    const int q    = lane >> 5;
    const int r    = lane & 31;

    {   // zero LDS (covers row pad)
        float4 z = {0.f, 0.f, 0.f, 0.f};
        float4* sz = (float4*)s_raw;
        for (int i = tid; i < LP * RSB / 16; i += 384) sz[i] = z;
    }
    __syncthreads();

    const float* gin = in + (size_t)b * (V * L);
    for (int i = tid; i < NQ * L; i += 384) {
        int q4 = i / L, p = i - q4 * L;
        const float* gp = gin + q4 * 4 * L + p;
        f16x4 hv = { (f16)gp[0], (f16)gp[L], (f16)gp[2 * L], (f16)gp[3 * L] };
        int off = (8 * q4) ^ (((p >> 3) & 3) << 4);
        *(f16x4*)(s_raw + p * RSB + off) = hv;
    }

    f16x8 bfr[KT][KSTEPS];
    #pragma unroll
    for (int t = 0; t < KT; ++t)
        #pragma unroll
        for (int ks = 0; ks < KSTEPS; ++ks)
            bfr[t][ks] = *(const f16x8*)(wp + (t * 96 + colw * 32 + r) * VP + ks * 16 + q * 8);

    __syncthreads();

    float runmax = -3.0e38f;
    for (int it = 0; it < NTILES / 2; ++it) {
        const int p0 = (roww * (NTILES / 2) + it) * 32;
        f32x16 acc = {};
        #pragma unroll
        for (int t = 0; t < KT; ++t) {
            int row = p0 + r + t;
            if (row > LP - 1) row = LP - 1;          // clamped row is zero
            const char* ap = s_raw + row * RSB;
            const int swz = ((row >> 3) & 3) << 4;
            #pragma unroll
            for (int ks = 0; ks < KSTEPS; ++ks) {
                f16x8 af = *(const f16x8*)(ap + ((ks * 32 + q * 16) ^ swz));
                acc = __builtin_amdgcn_mfma_f32_32x32x16_f16(af, bfr[t][ks], acc, 0, 0, 0);
            }
        }
        #pragma unroll
        for (int i = 0; i < 16; ++i) {
            int rr = (i & 3) + 8 * (i >> 2) + 4 * q;
            if (p0 + rr < LOUT) runmax = fmaxf(runmax, acc[i]);
        }
    }
    runmax = fmaxf(runmax, __shfl_xor(runmax, 32, 64));

    __syncthreads();
    float* s_red = (float*)s_raw;     // [2][96]
    if (lane < 32) s_red[roww * 96 + colw * 32 + r] = runmax;
    __syncthreads();
    if (tid < 96) {
        float m = fmaxf(s_red[tid], s_red[96 + tid]);
        feat[(size_t)b * 192 + feat_off + tid] = fmaxf(m + bias[tid], 0.f);
    }
}

// ---------------------------------------------------------------------------
// Gram + L2 normalize + readout (4 samples/block, one wave each).
// ---------------------------------------------------------------------------
__global__ __launch_bounds__(256) void gram_affinity_kernel(
    const float* __restrict__ feat, const float* __restrict__ w_aff,
    const float* __restrict__ b_aff, float* __restrict__ out, int B)
{
    const int lane = threadIdx.x & 63;
    const int wid  = threadIdx.x >> 6;
    const int b    = blockIdx.x * 4 + wid;

    __shared__ float s_x[4][192];

    if (b < B) {
        const float* fp = feat + (size_t)b * 192;
        for (int i = lane; i < 192; i += 64) s_x[wid][i] = fp[i];
    }
    __syncthreads();

    if (b < B) {
        float ssum = 0.f, sdot = 0.f;
        #pragma unroll
        for (int t = 0; t < 16; ++t) {
            const int jk = t * 64 + lane;
            const int j = jk >> 5, k = jk & 31;
            float gg = 0.f;
            #pragma unroll
            for (int i = 0; i < 6; ++i)
                gg = fmaf(s_x[wid][i * 32 + j], s_x[wid][i * 32 + k], gg);
            ssum = fmaf(gg, gg, ssum);
            sdot = fmaf(gg, w_aff[jk], sdot);
        }
        #pragma unroll
        for (int off = 32; off >= 1; off >>= 1) {
            ssum += __shfl_xor(ssum, off, 64);
            sdot += __shfl_xor(sdot, off, 64);
        }
        if (lane == 0) out[b] = sdot / (sqrtf(ssum) + 1e-12f) + b_aff[0];
    }
}

extern "C" void kernel_launch(void* const* d_in, const int* in_sizes, int n_in,
                              void* d_out, int out_size, void* d_ws, size_t ws_size,
                              hipStream_t stream)
{
    const float* protein = (const float*)d_in[0];  // (B, 25, 1000)
    const float* ligand  = (const float*)d_in[1];  // (B, 64, 100)
    const float* w_pro   = (const float*)d_in[2];  // (96, 25, 8)
    const float* b_pro   = (const float*)d_in[3];  // (96,)
    const float* w_lig   = (const float*)d_in[4];  // (96, 64, 4)
    const float* b_lig   = (const float*)d_in[5];  // (96,)
    const float* w_aff   = (const float*)d_in[6];  // (1024,)
    const float* b_aff   = (const float*)d_in[7];  // (1,)
    float* out = (float*)d_out;
    const int B = out_size;                        // 4096

    float* feat   = (float*)d_ws;                              // (B,192) f32
    f16*   wpackP = (f16*)((char*)d_ws + (size_t)B * 192 * 4); // 8*96*32 f16
    f16*   wpackL = wpackP + 8 * 96 * 32;                      // 4*96*64 f16

    repack_kernel<25, 8, 32><<<96, 256, 0, stream>>>(w_pro, wpackP);
    repack_kernel<64, 4, 64><<<96, 256, 0, stream>>>(w_lig, wpackL);

    // ligand branch -> feat[:, 0:96]
    conv_lig_kernel<<<B, 384, 0, stream>>>(ligand, wpackL, b_lig, feat, 0);
    // protein branch -> feat[:, 96:192]
    conv_pro_kernel<<<B, 256, 0, stream>>>(protein, wpackP, b_pro, feat, 96);

    gram_affinity_kernel<<<(B + 3) / 4, 256, 0, stream>>>(feat, w_aff, b_aff, out, B);
}